// Round 6
// baseline (5685.886 us; speedup 1.0000x reference)
//
#include <hip/hip_runtime.h>
#include <hip/hip_bf16.h>
#include <hip/hip_cooperative_groups.h>

namespace cg = cooperative_groups;

#define BB 16
#define TT 16
#define CC 128
#define HW 1024             // 32*32
#define PIX (CC*HW)         // 131072
#define STOT ((long)BB*PIX) // 2M

typedef short short8 __attribute__((ext_vector_type(8)));
typedef float f32x4  __attribute__((ext_vector_type(4)));

__device__ __forceinline__ float sigf(float x) { return 1.0f / (1.0f + __expf(-x)); }
__device__ __forceinline__ float tanhf_fast(float x) {
    float ax = fabsf(x);
    float t = __expf(-2.0f * ax);
    float r = (1.0f - t) / (1.0f + t);
    return copysignf(r, x);
}

// ---- packed hi/lo bf16: uint32 = (bf16(x)<<16) | bf16(x - bf16(x)) ----
__device__ __forceinline__ unsigned pack_hl(float x) {
    unsigned u = __float_as_uint(x);
    unsigned hi = (u + 0x7fffu + ((u >> 16) & 1u)) >> 16;
    float r = x - __uint_as_float(hi << 16);
    unsigned v = __float_as_uint(r);
    unsigned lo = (v + 0x7fffu + ((v >> 16) & 1u)) >> 16;
    return (hi << 16) | lo;
}
__device__ __forceinline__ float unpack_hl(unsigned p) {
    return __uint_as_float(p & 0xffff0000u) + __uint_as_float(p << 16);
}

__device__ __forceinline__ void split_frag(uint4 a, uint4 b, short8& hi, short8& lo) {
    unsigned w[8] = {a.x, a.y, a.z, a.w, b.x, b.y, b.z, b.w};
    union U { unsigned u[4]; short8 s; } h, l;
    #pragma unroll
    for (int j = 0; j < 4; ++j) {
        h.u[j] = (w[2*j] >> 16)      | (w[2*j+1] & 0xffff0000u);
        l.u[j] = (w[2*j] & 0xffffu)  | (w[2*j+1] << 16);
    }
    hi = h.s; lo = l.s;
}

// LDS tile addr: 128 rows x 32 k-words, stride 32 (16 KiB), XOR-quad swizzle.
// quad = (kw>>2) ^ (row&7); b128 accesses stay 16B aligned (kw%4==0).
__device__ __forceinline__ int taddr(int row, int kw) {
    return row * 32 + ((((kw >> 2) ^ (row & 7)) & 7) << 2) + (kw & 3);
}

// ---------------- MFMA GEMM tile (device fn) ----------------
// MODE 0: fp32 store (+ scalar bias[row])
// MODE 2: LSTM fuse: rows c*4+gate; st=Cst(f32), outv=Hp_new(packed)
// MODE 3: final fuse: rows c*4+gate(3 real+pad); st=mp(packed), outv=Hp_new, Hout optional
// B-source: m0>=m_split -> actB(kofs 0); k0>=k_split -> actB(kofs k_split); else actA.
// BF32: actB is fp32 (packed on the fly)
template<int MODE, bool BF32>
__device__ __forceinline__ void gemm_tile(
    unsigned* Ws, unsigned* Bs,
    const unsigned* __restrict__ Wp, const float* __restrict__ bias,
    const unsigned* __restrict__ actA, long sA,
    const void* __restrict__ actBv, long sB,
    int k_split, int m_split,
    void* __restrict__ outv, void* __restrict__ stv, float* __restrict__ Hout,
    int M, int K, int b, int n0, int m0)
{
    const int tid = threadIdx.x;
    const int lane = tid & 63;
    const int w  = tid >> 6;
    const int wm = w & 1, wn = w >> 1;
    const int g  = lane >> 4, pl = lane & 15;

    f32x4 acc[4][4] = {};

    for (int k0 = 0; k0 < K; k0 += 32) {
        // stage A (weights): 8 threads/row, 128B contiguous per row
        #pragma unroll
        for (int it = 0; it < 4; ++it) {
            int idx = tid + 256 * it;
            int row = idx >> 3, kq = idx & 7;
            uint4 v = *(const uint4*)(Wp + (long)(m0 + row) * K + k0 + 4 * kq);
            *(uint4*)(Ws + taddr(row, 4 * kq)) = v;
        }
        // stage B (activations), register 4x4 transpose -> [pixel][k]
        {
            const int kq = tid & 7, p4 = tid >> 3;   // kq 0..7, p4 0..31
            const bool useB = (m0 >= m_split) || (k0 >= k_split);
            const int kofs = (m0 >= m_split) ? 0 : k_split;
            uint4 v[4];
            if (BF32 && useB) {
                const float* src = (const float*)actBv + (long)b * sB;
                #pragma unroll
                for (int i = 0; i < 4; ++i) {
                    int kc = k0 + 4 * kq + i - kofs;
                    float4 f = *(const float4*)(src + (long)kc * HW + n0 + 4 * p4);
                    v[i].x = pack_hl(f.x); v[i].y = pack_hl(f.y);
                    v[i].z = pack_hl(f.z); v[i].w = pack_hl(f.w);
                }
            } else {
                const unsigned* src = useB ? ((const unsigned*)actBv + (long)b * sB)
                                           : (actA + (long)b * sA);
                #pragma unroll
                for (int i = 0; i < 4; ++i) {
                    int kc = k0 + 4 * kq + i - (useB ? kofs : 0);
                    v[i] = *(const uint4*)(src + (long)kc * HW + n0 + 4 * p4);
                }
            }
            #pragma unroll
            for (int j = 0; j < 4; ++j) {
                uint4 wv;
                wv.x = ((const unsigned*)&v[0])[j];
                wv.y = ((const unsigned*)&v[1])[j];
                wv.z = ((const unsigned*)&v[2])[j];
                wv.w = ((const unsigned*)&v[3])[j];
                *(uint4*)(Bs + taddr(4 * p4 + j, 4 * kq)) = wv;
            }
        }
        __syncthreads();

        short8 ahi[4], alo[4], bhi[4], blo[4];
        #pragma unroll
        for (int mt = 0; mt < 4; ++mt) {
            int row = 64 * wm + 16 * mt + pl;
            uint4 w0 = *(const uint4*)(Ws + taddr(row, 8 * g));
            uint4 w1 = *(const uint4*)(Ws + taddr(row, 8 * g + 4));
            split_frag(w0, w1, ahi[mt], alo[mt]);
        }
        #pragma unroll
        for (int nt = 0; nt < 4; ++nt) {
            int prow = 64 * wn + 16 * nt + pl;
            uint4 w0 = *(const uint4*)(Bs + taddr(prow, 8 * g));
            uint4 w1 = *(const uint4*)(Bs + taddr(prow, 8 * g + 4));
            split_frag(w0, w1, bhi[nt], blo[nt]);
        }
        #pragma unroll
        for (int mt = 0; mt < 4; ++mt)
            #pragma unroll
            for (int nt = 0; nt < 4; ++nt) {
                acc[mt][nt] = __builtin_amdgcn_mfma_f32_16x16x32_bf16(ahi[mt], bhi[nt], acc[mt][nt], 0, 0, 0);
                acc[mt][nt] = __builtin_amdgcn_mfma_f32_16x16x32_bf16(ahi[mt], blo[nt], acc[mt][nt], 0, 0, 0);
                acc[mt][nt] = __builtin_amdgcn_mfma_f32_16x16x32_bf16(alo[mt], bhi[nt], acc[mt][nt], 0, 0, 0);
            }
        __syncthreads();
    }

    if (MODE == 0) {
        #pragma unroll
        for (int mt = 0; mt < 4; ++mt)
            #pragma unroll
            for (int r = 0; r < 4; ++r) {
                int row = m0 + 64 * wm + 16 * mt + 4 * g + r;
                float bb = bias[row];
                #pragma unroll
                for (int nt = 0; nt < 4; ++nt) {
                    int col = n0 + 64 * wn + 16 * nt + pl;
                    ((float*)outv)[((long)b * M + row) * HW + col] = acc[mt][nt][r] + bb;
                }
            }
    } else {
        // rows interleaved c*4+gate: one thread's f32x4 = all 4 gates of channel c
        const float4* bias4 = (const float4*)bias;
        unsigned* Hp = (unsigned*)outv;
        #pragma unroll
        for (int mt = 0; mt < 4; ++mt) {
            int c = (m0 >> 2) + 16 * wm + 4 * mt + g;
            float4 bb = bias4[c];
            #pragma unroll
            for (int nt = 0; nt < 4; ++nt) {
                int p = n0 + 64 * wn + 16 * nt + pl;
                long idx = (long)b * PIX + (long)c * HW + p;
                float v0 = acc[mt][nt][0] + bb.x;
                float v1 = acc[mt][nt][1] + bb.y;
                float v2 = acc[mt][nt][2] + bb.z;
                float v3 = acc[mt][nt][3] + bb.w;
                if (MODE == 2) {
                    float* Cst = (float*)stv;
                    float cc = Cst[idx] * sigf(v0) + sigf(v1) * tanhf_fast(v2);
                    Cst[idx] = cc;
                    Hp[idx] = pack_hl(sigf(v3) * tanhf_fast(cc));
                } else {
                    unsigned* mp = (unsigned*)stv;
                    float ot = sigf(v0), gt = tanhf_fast(v1), it = sigf(v2);
                    float mo = unpack_hl(mp[idx]);
                    float mn = gt * it + (1.0f - it) * mo;
                    mp[idx] = pack_hl(mn);
                    float hv = ot * mn;
                    Hp[idx] = pack_hl(hv);
                    if (Hout) Hout[idx] = hv;
                }
            }
        }
    }
}

// ---------------- attention (device fn): one (b,c) 32x32 image, 256 threads ----------------
__device__ __forceinline__ void attn_img(float* qs, const float* __restrict__ VKM,
                                         unsigned* __restrict__ ZHZM, int img)
{
    const int tid = threadIdx.x;
    const int b = img >> 7, c = img & 127;
    const long base  = ((long)b * 640 + c) * HW;
    const long obase = ((long)b * 256 + c) * HW;

    __syncthreads();   // protect qs reuse across images
    #pragma unroll
    for (int it = 0; it < 4; ++it) {
        int p = it * 256 + tid;
        qs[(p >> 5) * 33 + (p & 31)] = VKM[base + 256l * HW + p];
    }
    __syncthreads();
    #pragma unroll
    for (int it = 0; it < 4; ++it) {
        int p = it * 256 + tid;
        int i = p >> 5, j = p & 31;
        float qhT = qs[j * 33 + i];
        float vh  = VKM[base + p];
        float kh  = VKM[base + 128l * HW + p];
        float km  = VKM[base + 384l * HW + p];
        float vm  = VKM[base + 512l * HW + p];

        float sh = kh * qhT, sm = qhT * km;
        float mh = sh, mm = sm;
        #pragma unroll
        for (int o = 16; o > 0; o >>= 1) {
            mh = fmaxf(mh, __shfl_xor(mh, o, 32));
            mm = fmaxf(mm, __shfl_xor(mm, o, 32));
        }
        float eh = __expf(sh - mh), em = __expf(sm - mm);
        float s1 = eh, s2 = em;
        #pragma unroll
        for (int o = 16; o > 0; o >>= 1) {
            s1 += __shfl_xor(s1, o, 32);
            s2 += __shfl_xor(s2, o, 32);
        }
        ZHZM[obase + p]             = pack_hl(vh * (eh / s1));
        ZHZM[obase + 128l * HW + p] = pack_hl(vm * (em / s2));
    }
}

// ---------------- persistent cooperative mega-kernel (LDS = 32 KiB exactly) ----------------
__global__ __launch_bounds__(256, 2) void mega(
    const float* __restrict__ x,
    const unsigned* __restrict__ Wp5, const float* __restrict__ b5,
    const unsigned* __restrict__ Wg, const float* __restrict__ bg4,
    const unsigned* __restrict__ Wo, const float* __restrict__ bo4,
    unsigned* Ha, unsigned* Hb, unsigned* mp, float* Cst,
    float* VKM, unsigned* ZHZM, float* out)
{
    __shared__ __align__(16) unsigned Ws[128 * 32];
    __shared__ __align__(16) unsigned Bs[128 * 32];

    cg::grid_group grid = cg::this_grid();
    const int blk = blockIdx.x;   // 0..511
    const int BIG = 1 << 30;

    #pragma unroll 1
    for (int t = 0; t < TT; ++t) {
        // phase 1: gates = Wg * [Hb ; x_t], fused LSTM -> Cst, Ha  (M=512,K=256)
        {
            int n0 = (blk & 7) * 128, m0 = ((blk >> 3) & 3) * 128, b = blk >> 5;
            gemm_tile<2, true>(Ws, Bs, Wg, bg4, Hb, (long)PIX,
                               x + (long)t * PIX, (long)TT * PIX,
                               128, BIG, Ha, Cst, nullptr, 512, 256, b, n0, m0);
        }
        grid.sync();
        // phase 2: vh,kh,qh (Ha) + km,vm (mp)  (M=640,K=128) -> VKM fp32; 640 tiles
        #pragma unroll 1
        for (int t2 = blk; t2 < 640; t2 += 512) {
            int n0 = (t2 & 7) * 128;
            int r = t2 >> 3;
            int m = r % 5, b = r / 5;
            gemm_tile<0, false>(Ws, Bs, Wp5, b5, Ha, (long)PIX, mp, (long)PIX,
                                BIG, 384, VKM, nullptr, nullptr, 640, 128, b, n0, m * 128);
        }
        grid.sync();
        // phase 3: attention, 2048 images, 4 per block
        {
            float* qs = (float*)Ws;
            #pragma unroll 1
            for (int ii = 0; ii < 4; ++ii)
                attn_img(qs, VKM, ZHZM, blk * 4 + ii);
        }
        grid.sync();
        // phase 4: o,g,i = Wo * [Ha ; ZHZM], fused final -> mp, Hb (+out at t=15)
        {
            int n0 = (blk & 7) * 128, m0 = ((blk >> 3) & 3) * 128, b = blk >> 5;
            gemm_tile<3, false>(Ws, Bs, Wo, bo4, Ha, (long)PIX, ZHZM, 2l * PIX,
                                128, BIG, Hb, mp, (t == TT - 1) ? out : nullptr,
                                512, 384, b, n0, m0);
        }
        grid.sync();
    }
}

// ---------------- standalone fallback kernels (round-4 structure) ----------------
template<int MODE, bool BF32>
__global__ __launch_bounds__(256, 2) void gemm_g(
    const unsigned* __restrict__ Wp, const float* __restrict__ bias,
    const unsigned* __restrict__ actA, long sA,
    const void* __restrict__ actBv, long sB,
    int k_split, int m_split,
    void* __restrict__ outv, void* __restrict__ stv, float* __restrict__ Hout,
    int M, int K)
{
    __shared__ __align__(16) unsigned Ws[128 * 32];
    __shared__ __align__(16) unsigned Bs[128 * 32];
    gemm_tile<MODE, BF32>(Ws, Bs, Wp, bias, actA, sA, actBv, sB, k_split, m_split,
                          outv, stv, Hout, M, K, blockIdx.z, blockIdx.x * 128, blockIdx.y * 128);
}

__global__ __launch_bounds__(256) void attn_g(const float* __restrict__ VKM,
                                              unsigned* __restrict__ ZHZM)
{
    __shared__ float qs[32 * 33];
    attn_img(qs, VKM, ZHZM, blockIdx.x);
}

// ---------------- one-shot setup: pack W5, build Wg (rows c*4+gate), Wo (composite) ----------------
__global__ __launch_bounds__(256) void setup_all(
    const float* __restrict__ W5, const float* __restrict__ W8, const float* __restrict__ b8,
    unsigned* __restrict__ Wp5,
    unsigned* __restrict__ Wg, float* __restrict__ bg4,
    unsigned* __restrict__ Wo, float* __restrict__ bo4)
{
    int idx = blockIdx.x * 256 + threadIdx.x;
    if (idx < 81920) {                       // pack W5 [640][128]
        Wp5[idx] = pack_hl(W5[idx]);
        return;
    }
    idx -= 81920;
    if (idx < 131072) {                      // Wg: rows c*4+gate, convs 10..13 (W8[4..7]), K=256
        int rr = idx >> 8, k = idx & 255;
        int c = rr >> 2, gg = rr & 3;
        Wg[idx] = pack_hl(W8[((long)(4 + gg) * 128 + c) * 256 + k]);
        if (k == 0) bg4[rr] = b8[(4 + gg) * 128 + c];
        return;
    }
    idx -= 131072;                           // Wo: 512 rows x 384, conv6 folded
    if (idx >= 512 * 384) return;
    int rr = idx / 384, k = idx - rr * 384;
    int c = rr >> 2, gg = rr & 3;
    float wv = 0.0f;
    if (gg < 3) {
        const float* wr = W8 + ((long)(1 + gg) * 128 + c) * 256;
        if (k < 128) {
            wv = wr[k];
        } else {
            int i = k - 128;
            float s = 0.0f;
            for (int j = 0; j < 128; ++j)
                s += wr[128 + j] * W8[(long)j * 256 + i];   // Wz = W8[0]
            wv = s;
        }
    }
    Wo[(long)rr * 384 + k] = pack_hl(wv);
    if (k == 0) {
        float bb = 0.0f;
        if (gg < 3) {
            bb = b8[(1 + gg) * 128 + c];
            const float* wr = W8 + ((long)(1 + gg) * 128 + c) * 256;
            for (int j = 0; j < 128; ++j) bb += wr[128 + j] * b8[j];  // bz = b8[0]
        }
        bo4[rr] = bb;
    }
}

extern "C" void kernel_launch(void* const* d_in, const int* in_sizes, int n_in,
                              void* d_out, int out_size, void* d_ws, size_t ws_size,
                              hipStream_t stream)
{
    const float* x  = (const float*)d_in[0];   // [16][16][128][1024]
    const float* c0 = (const float*)d_in[1];
    const float* W5 = (const float*)d_in[2];   // [640][128]
    const float* b5 = (const float*)d_in[3];   // [640]
    const float* W8 = (const float*)d_in[4];   // [8][128][256]
    const float* b8 = (const float*)d_in[5];   // [8][128]
    float* out = (float*)d_out;

    const long S = STOT;
    unsigned* Ha   = (unsigned*)d_ws;          // S  (intra-step H)
    unsigned* Hb   = Ha + S;                   // S  (cross-step H)
    unsigned* mp   = Hb + S;                   // S
    float*    Cst  = (float*)(mp + S);         // S
    unsigned* Wp5  = (unsigned*)(Cst + S);     // 81920
    unsigned* Wg   = Wp5 + 81920;              // 131072
    unsigned* Wo   = Wg + 131072;              // 196608 (512x384)
    float*    bg4  = (float*)(Wo + 196608);    // 512
    float*    bo4  = bg4 + 512;                // 512
    float*    VKM  = bo4 + 512;                // 5S fp32
    unsigned* ZHZM = (unsigned*)(VKM + 5 * S); // 2S

    hipMemsetAsync(Hb, 0, S * sizeof(unsigned), stream);
    hipMemsetAsync(mp, 0, S * sizeof(unsigned), stream);
    hipMemcpyAsync(Cst, c0, S * sizeof(float), hipMemcpyDeviceToDevice, stream);

    setup_all<<<1600, dim3(256), 0, stream>>>(W5, W8, b8, Wp5, Wg, bg4, Wo, bo4);

    void* args[] = {
        (void*)&x, (void*)&Wp5, (void*)&b5, (void*)&Wg, (void*)&bg4,
        (void*)&Wo, (void*)&bo4, (void*)&Ha, (void*)&Hb, (void*)&mp,
        (void*)&Cst, (void*)&VKM, (void*)&ZHZM, (void*)&out
    };
    hipError_t ce = hipLaunchCooperativeKernel((void*)mega, dim3(512), dim3(256),
                                               args, 0, stream);
    if (ce != hipSuccess) {
        // fallback: proven 4-dispatch-per-step sequence
        const int BIG = 1 << 30;
        const dim3 blk(256);
        for (int t = 0; t < TT; ++t) {
            gemm_g<2, true><<<dim3(8, 4, 16), blk, 0, stream>>>(
                Wg, bg4, Hb, (long)PIX, x + (long)t * PIX, (long)TT * PIX,
                128, BIG, Ha, Cst, nullptr, 512, 256);
            gemm_g<0, false><<<dim3(8, 5, 16), blk, 0, stream>>>(
                Wp5, b5, Ha, (long)PIX, mp, (long)PIX,
                BIG, 384, VKM, nullptr, nullptr, 640, 128);
            attn_g<<<2048, blk, 0, stream>>>(VKM, ZHZM);
            gemm_g<3, false><<<dim3(8, 4, 16), blk, 0, stream>>>(
                Wo, bo4, Ha, (long)PIX, ZHZM, 2l * PIX,
                128, BIG, Hb, mp, (t == TT - 1) ? out : nullptr, 512, 384);
        }
    }
}

// Round 7
// 1570.621 us; speedup vs baseline: 3.6202x; 3.6202x over previous
//
#include <hip/hip_runtime.h>
#include <hip/hip_bf16.h>

#define BB 16
#define TT 16
#define CC 128
#define HW 1024             // 32*32
#define PIX (CC*HW)         // 131072
#define STOT ((long)BB*PIX) // 2M

typedef short short8 __attribute__((ext_vector_type(8)));
typedef float f32x4  __attribute__((ext_vector_type(4)));

__device__ __forceinline__ float sigf(float x) { return 1.0f / (1.0f + __expf(-x)); }
__device__ __forceinline__ float tanhf_fast(float x) {
    float ax = fabsf(x);
    float t = __expf(-2.0f * ax);
    float r = (1.0f - t) / (1.0f + t);
    return copysignf(r, x);
}

// ---- packed hi/lo bf16: uint32 = (bf16(x)<<16) | bf16(x - bf16(x)) ----
__device__ __forceinline__ unsigned pack_hl(float x) {
    unsigned u = __float_as_uint(x);
    unsigned hi = (u + 0x7fffu + ((u >> 16) & 1u)) >> 16;
    float r = x - __uint_as_float(hi << 16);
    unsigned v = __float_as_uint(r);
    unsigned lo = (v + 0x7fffu + ((v >> 16) & 1u)) >> 16;
    return (hi << 16) | lo;
}
__device__ __forceinline__ float unpack_hl(unsigned p) {
    return __uint_as_float(p & 0xffff0000u) + __uint_as_float(p << 16);
}
__device__ __forceinline__ unsigned short pack_bf16(float x) {
    unsigned u = __float_as_uint(x);
    return (unsigned short)((u + 0x7fffu + ((u >> 16) & 1u)) >> 16);
}
__device__ __forceinline__ float bf16f(unsigned short s) {
    return __uint_as_float(((unsigned)s) << 16);
}

__device__ __forceinline__ void split_frag(uint4 a, uint4 b, short8& hi, short8& lo) {
    unsigned w[8] = {a.x, a.y, a.z, a.w, b.x, b.y, b.z, b.w};
    union U { unsigned u[4]; short8 s; } h, l;
    #pragma unroll
    for (int j = 0; j < 4; ++j) {
        h.u[j] = (w[2*j] >> 16)      | (w[2*j+1] & 0xffff0000u);
        l.u[j] = (w[2*j] & 0xffffu)  | (w[2*j+1] << 16);
    }
    hi = h.s; lo = l.s;
}

// LDS tile addr: 128 rows x 32 k-words, stride 36, quad rotate (proven in R2-R4)
__device__ __forceinline__ int taddr(int row, int kw) {
    return row * 36 + ((((kw >> 2) + (row >> 2)) & 7) << 2) + (kw & 3);
}

// ---------------- MFMA GEMM with fused epilogues ----------------
// MODE 1: bf16 store (+ scalar bias[row])        -> outv = ushort*
// MODE 2: LSTM fuse: rows c*4+gate; stv=Cst(f32), outv=Hp_new(packed)
// MODE 3: final fuse: rows c*4+gate(3+pad); stv=mp(packed), outv=Hp_new, Hout opt fp32
// B-source: m0>=m_split -> actB(kofs 0); k0>=k_split -> actB(kofs k_split); else actA.
// BKIND: 0 = actB packed u32, 1 = actB fp32 (pack on fly), 2 = actB bf16 (expand hi)
template<int MODE, int BKIND>
__global__ __launch_bounds__(256, 2) void gemm_mfma(
    const unsigned* __restrict__ Wp, const float* __restrict__ bias,
    const unsigned* __restrict__ actA, long sA,
    const void* __restrict__ actBv, long sB,
    int k_split, int m_split,
    void* __restrict__ outv, void* __restrict__ stv, float* __restrict__ Hout,
    int M, int K)
{
    __shared__ __align__(16) unsigned Ws[128 * 36];
    __shared__ __align__(16) unsigned Bs[128 * 36];

    const int b  = blockIdx.z;
    const int n0 = blockIdx.x * 128;
    const int m0 = blockIdx.y * 128;
    const int t  = threadIdx.x;
    const int lane = t & 63;
    const int w  = t >> 6;
    const int wm = w & 1, wn = w >> 1;
    const int g  = lane >> 4, pl = lane & 15;

    f32x4 acc[4][4] = {};

    for (int k0 = 0; k0 < K; k0 += 32) {
        // stage A (weights)
        #pragma unroll
        for (int it = 0; it < 4; ++it) {
            int idx = t + 256 * it;
            int row = idx >> 3, kq = idx & 7;
            uint4 v = *(const uint4*)(Wp + (long)(m0 + row) * K + k0 + 4 * kq);
            *(uint4*)(Ws + taddr(row, 4 * kq)) = v;
        }
        // stage B (activations), register 4x4 transpose -> [pixel][k]
        {
            const int p4 = t & 31, kq = t >> 5;
            const bool useB = (m0 >= m_split) || (k0 >= k_split);
            const int kofs = (m0 >= m_split) ? 0 : k_split;
            uint4 v[4];
            if (BKIND == 1 && useB) {
                const float* src = (const float*)actBv + (long)b * sB;
                #pragma unroll
                for (int i = 0; i < 4; ++i) {
                    int kc = k0 + 4 * kq + i - kofs;
                    float4 f = *(const float4*)(src + (long)kc * HW + n0 + 4 * p4);
                    v[i].x = pack_hl(f.x); v[i].y = pack_hl(f.y);
                    v[i].z = pack_hl(f.z); v[i].w = pack_hl(f.w);
                }
            } else if (BKIND == 2 && useB) {
                const unsigned short* src = (const unsigned short*)actBv + (long)b * sB;
                #pragma unroll
                for (int i = 0; i < 4; ++i) {
                    int kc = k0 + 4 * kq + i - kofs;
                    uint2 u = *(const uint2*)(src + (long)kc * HW + n0 + 4 * p4);
                    v[i].x = u.x << 16;
                    v[i].y = u.x & 0xffff0000u;
                    v[i].z = u.y << 16;
                    v[i].w = u.y & 0xffff0000u;
                }
            } else {
                const unsigned* src = useB ? ((const unsigned*)actBv + (long)b * sB)
                                           : (actA + (long)b * sA);
                #pragma unroll
                for (int i = 0; i < 4; ++i) {
                    int kc = k0 + 4 * kq + i - (useB ? kofs : 0);
                    v[i] = *(const uint4*)(src + (long)kc * HW + n0 + 4 * p4);
                }
            }
            #pragma unroll
            for (int j = 0; j < 4; ++j) {
                uint4 wv;
                wv.x = ((const unsigned*)&v[0])[j];
                wv.y = ((const unsigned*)&v[1])[j];
                wv.z = ((const unsigned*)&v[2])[j];
                wv.w = ((const unsigned*)&v[3])[j];
                *(uint4*)(Bs + taddr(4 * p4 + j, 4 * kq)) = wv;
            }
        }
        __syncthreads();

        short8 ahi[4], alo[4], bhi[4], blo[4];
        #pragma unroll
        for (int mt = 0; mt < 4; ++mt) {
            int row = 64 * wm + 16 * mt + pl;
            uint4 w0 = *(const uint4*)(Ws + taddr(row, 8 * g));
            uint4 w1 = *(const uint4*)(Ws + taddr(row, 8 * g + 4));
            split_frag(w0, w1, ahi[mt], alo[mt]);
        }
        #pragma unroll
        for (int nt = 0; nt < 4; ++nt) {
            int prow = 64 * wn + 16 * nt + pl;
            uint4 w0 = *(const uint4*)(Bs + taddr(prow, 8 * g));
            uint4 w1 = *(const uint4*)(Bs + taddr(prow, 8 * g + 4));
            split_frag(w0, w1, bhi[nt], blo[nt]);
        }
        #pragma unroll
        for (int mt = 0; mt < 4; ++mt)
            #pragma unroll
            for (int nt = 0; nt < 4; ++nt) {
                acc[mt][nt] = __builtin_amdgcn_mfma_f32_16x16x32_bf16(ahi[mt], bhi[nt], acc[mt][nt], 0, 0, 0);
                acc[mt][nt] = __builtin_amdgcn_mfma_f32_16x16x32_bf16(ahi[mt], blo[nt], acc[mt][nt], 0, 0, 0);
                acc[mt][nt] = __builtin_amdgcn_mfma_f32_16x16x32_bf16(alo[mt], bhi[nt], acc[mt][nt], 0, 0, 0);
            }
        __syncthreads();
    }

    if (MODE == 1) {
        #pragma unroll
        for (int mt = 0; mt < 4; ++mt)
            #pragma unroll
            for (int r = 0; r < 4; ++r) {
                int row = m0 + 64 * wm + 16 * mt + 4 * g + r;
                float bb = bias[row];
                #pragma unroll
                for (int nt = 0; nt < 4; ++nt) {
                    int col = n0 + 64 * wn + 16 * nt + pl;
                    ((unsigned short*)outv)[((long)b * M + row) * HW + col] =
                        pack_bf16(acc[mt][nt][r] + bb);
                }
            }
    } else {
        // rows interleaved c*4+gate: one thread's f32x4 = all 4 gates of channel c
        const float4* bias4 = (const float4*)bias;
        unsigned* Hp = (unsigned*)outv;
        #pragma unroll
        for (int mt = 0; mt < 4; ++mt) {
            int c = (m0 >> 2) + 16 * wm + 4 * mt + g;
            float4 bb = bias4[c];
            #pragma unroll
            for (int nt = 0; nt < 4; ++nt) {
                int p = n0 + 64 * wn + 16 * nt + pl;
                long idx = (long)b * PIX + (long)c * HW + p;
                float v0 = acc[mt][nt][0] + bb.x;
                float v1 = acc[mt][nt][1] + bb.y;
                float v2 = acc[mt][nt][2] + bb.z;
                float v3 = acc[mt][nt][3] + bb.w;
                if (MODE == 2) {
                    float* Cst = (float*)stv;
                    float cc = Cst[idx] * sigf(v0) + sigf(v1) * tanhf_fast(v2);
                    Cst[idx] = cc;
                    Hp[idx] = pack_hl(sigf(v3) * tanhf_fast(cc));
                } else {
                    unsigned* mp = (unsigned*)stv;
                    float ot = sigf(v0), gt = tanhf_fast(v1), it = sigf(v2);
                    float mo = unpack_hl(mp[idx]);
                    float mn = gt * it + (1.0f - it) * mo;
                    mp[idx] = pack_hl(mn);
                    float hv = ot * mn;
                    Hp[idx] = pack_hl(hv);
                    if (Hout) Hout[idx] = hv;
                }
            }
        }
    }
}

// ---------------- attention: VKM bf16 [16][640][1024] -> ZHZM bf16 [16][256][1024] ----------------
__global__ __launch_bounds__(1024) void attn_kernel(
    const unsigned short* __restrict__ VKM, unsigned short* __restrict__ ZHZM)
{
    __shared__ float qs[32 * 33];
    const int tid = threadIdx.x;
    const int b = blockIdx.x >> 7, c = blockIdx.x & 127;
    const long base  = ((long)b * 640 + c) * HW;
    const long obase = ((long)b * 256 + c) * HW;

    qs[(tid >> 5) * 33 + (tid & 31)] = bf16f(VKM[base + 256l * HW + tid]);
    __syncthreads();

    const int i = tid >> 5, j = tid & 31;
    float qhT = qs[j * 33 + i];
    float vh  = bf16f(VKM[base + tid]);
    float kh  = bf16f(VKM[base + 128l * HW + tid]);
    float km  = bf16f(VKM[base + 384l * HW + tid]);
    float vm  = bf16f(VKM[base + 512l * HW + tid]);

    float sh = kh * qhT, sm = qhT * km;
    float mh = sh, mm = sm;
    #pragma unroll
    for (int o = 16; o > 0; o >>= 1) {
        mh = fmaxf(mh, __shfl_xor(mh, o, 32));
        mm = fmaxf(mm, __shfl_xor(mm, o, 32));
    }
    float eh = __expf(sh - mh), em = __expf(sm - mm);
    float s1 = eh, s2 = em;
    #pragma unroll
    for (int o = 16; o > 0; o >>= 1) {
        s1 += __shfl_xor(s1, o, 32);
        s2 += __shfl_xor(s2, o, 32);
    }
    ZHZM[obase + tid]             = pack_bf16(vh * (eh / s1));
    ZHZM[obase + 128l * HW + tid] = pack_bf16(vm * (em / s2));
}

// ---------------- one-shot setup: pack W5, build Wg (rows c*4+gate), Wo (composite) ----------------
__global__ __launch_bounds__(256) void setup_all(
    const float* __restrict__ W5, const float* __restrict__ W8, const float* __restrict__ b8,
    unsigned* __restrict__ Wp5,
    unsigned* __restrict__ Wg, float* __restrict__ bg4,
    unsigned* __restrict__ Wo, float* __restrict__ bo4)
{
    int idx = blockIdx.x * 256 + threadIdx.x;
    if (idx < 81920) {                       // pack W5 [640][128]
        Wp5[idx] = pack_hl(W5[idx]);
        return;
    }
    idx -= 81920;
    if (idx < 131072) {                      // Wg: rows c*4+gate, convs 10..13 (W8[4..7]), K=256
        int rr = idx >> 8, k = idx & 255;
        int c = rr >> 2, gg = rr & 3;
        Wg[idx] = pack_hl(W8[((long)(4 + gg) * 128 + c) * 256 + k]);
        if (k == 0) bg4[rr] = b8[(4 + gg) * 128 + c];
        return;
    }
    idx -= 131072;                           // Wo: 512 rows x 384, conv6 folded
    if (idx >= 512 * 384) return;
    int rr = idx / 384, k = idx - rr * 384;
    int c = rr >> 2, gg = rr & 3;
    float wv = 0.0f;
    if (gg < 3) {
        const float* wr = W8 + ((long)(1 + gg) * 128 + c) * 256;
        if (k < 128) {
            wv = wr[k];
        } else {
            int i = k - 128;
            float s = 0.0f;
            for (int j = 0; j < 128; ++j)
                s += wr[128 + j] * W8[(long)j * 256 + i];   // Wz = W8[0]
            wv = s;
        }
    }
    Wo[(long)rr * 384 + k] = pack_hl(wv);
    if (k == 0) {
        float bb = 0.0f;
        if (gg < 3) {
            bb = b8[(1 + gg) * 128 + c];
            const float* wr = W8 + ((long)(1 + gg) * 128 + c) * 256;
            for (int j = 0; j < 128; ++j) bb += wr[128 + j] * b8[j];  // bz = b8[0]
        }
        bo4[rr] = bb;
    }
}

extern "C" void kernel_launch(void* const* d_in, const int* in_sizes, int n_in,
                              void* d_out, int out_size, void* d_ws, size_t ws_size,
                              hipStream_t stream)
{
    const float* x  = (const float*)d_in[0];   // [16][16][128][1024]
    const float* c0 = (const float*)d_in[1];
    const float* W5 = (const float*)d_in[2];   // [640][128]
    const float* b5 = (const float*)d_in[3];   // [640]
    const float* W8 = (const float*)d_in[4];   // [8][128][256]
    const float* b8 = (const float*)d_in[5];   // [8][128]
    float* out = (float*)d_out;

    const long S = STOT;
    unsigned* Ha   = (unsigned*)d_ws;          // S  (intra-step H, packed hl)
    unsigned* Hb   = Ha + S;                   // S  (cross-step H, packed hl)
    unsigned* mp   = Hb + S;                   // S  (memory state, packed hl)
    float*    Cst  = (float*)(mp + S);         // S  fp32
    unsigned* Wp5  = (unsigned*)(Cst + S);     // 81920
    unsigned* Wg   = Wp5 + 81920;              // 131072
    unsigned* Wo   = Wg + 131072;              // 196608 (512x384)
    float*    bg4  = (float*)(Wo + 196608);    // 512
    float*    bo4  = bg4 + 512;                // 512
    unsigned short* VKM  = (unsigned short*)(bo4 + 512);   // 5S bf16
    unsigned short* ZHZM = VKM + 5 * S;                    // 2S bf16

    hipMemsetAsync(Hb, 0, S * sizeof(unsigned), stream);
    hipMemsetAsync(mp, 0, S * sizeof(unsigned), stream);
    hipMemcpyAsync(Cst, c0, S * sizeof(float), hipMemcpyDeviceToDevice, stream);

    setup_all<<<1600, dim3(256), 0, stream>>>(W5, W8, b8, Wp5, Wg, bg4, Wo, bo4);

    const int BIG = 1 << 30;
    const dim3 blk(256);
    for (int t = 0; t < TT; ++t) {
        // gates = Wg * [Hb ; x_t], fused LSTM -> Cst, Ha   (M=512, K=256)
        gemm_mfma<2, 1><<<dim3(8, 4, 16), blk, 0, stream>>>(
            Wg, bg4, Hb, (long)PIX, x + (long)t * PIX, (long)TT * PIX,
            128, BIG, Ha, Cst, nullptr, 512, 256);

        // vh,kh,qh (Ha) + km,vm (mp)   (M=640, K=128) -> VKM bf16
        gemm_mfma<1, 0><<<dim3(8, 5, 16), blk, 0, stream>>>(
            Wp5, b5, Ha, (long)PIX, mp, (long)PIX,
            BIG, 384, VKM, nullptr, nullptr, 640, 128);

        attn_kernel<<<2048, dim3(1024), 0, stream>>>(VKM, ZHZM);

        // o,g,i = Wo * [Ha ; ZHZM(bf16)] (conv6 folded), fused final -> mp, Hb (+out)
        gemm_mfma<3, 2><<<dim3(8, 4, 16), blk, 0, stream>>>(
            Wo, bo4, Ha, (long)PIX, ZHZM, 2l * PIX,
            128, BIG, Hb, mp, (t == TT - 1) ? out : nullptr, 512, 384);
    }
}